// Round 3
// baseline (262.690 us; speedup 1.0000x reference)
//
#include <hip/hip_runtime.h>
#include <hip/hip_fp16.h>

// SpMM (segment-sum of scaled gathered rows), faithful to:
//   H = fp16(m); v = fp16(vals); out = fp32(segment_sum(H[col] * v[:,None], row))
// N=50000 rows, NNZ=800000 edges (row sorted ascending), D=256.
//
// Strategy: 1 block (256 threads = 4 waves) per output row r.
//   - binary search sorted `row` for segment [start, end)
//   - thread d accumulates over edges: fp32 += fp16(vals[e]) * fp16(m[col[e]][d])
//   - coalesced gather: 256 consecutive floats per edge.

#define D 256

__device__ __forceinline__ int lower_bound(const int* __restrict__ a, int n, int key) {
    int lo = 0, hi = n;
    while (lo < hi) {
        int mid = (lo + hi) >> 1;
        if (a[mid] < key) lo = mid + 1;
        else hi = mid;
    }
    return lo;
}

__global__ __launch_bounds__(D) void NaiveMerge_spmm_kernel(
        const float* __restrict__ m,
        const int* __restrict__ row,
        const int* __restrict__ col,
        const float* __restrict__ vals,
        float* __restrict__ out,
        int nnz) {
    const int r = blockIdx.x;
    const int d = threadIdx.x;

    // Wave-uniform binary searches (all lanes same path; loads broadcast/cached).
    const int start = lower_bound(row, nnz, r);
    const int end   = lower_bound(row, nnz, r + 1);

    float acc = 0.0f;
    for (int e = start; e < end; ++e) {
        const int   c = col[e];            // block-uniform
        const float v = vals[e];           // block-uniform
        const __half hv = __float2half(v);
        const __half hm = __float2half(m[(size_t)c * D + d]);  // coalesced gather
        acc += __half2float(__hmul(hm, hv));                   // fp16 product, fp32 accum
    }
    out[(size_t)r * D + d] = acc;
}

extern "C" void kernel_launch(void* const* d_in, const int* in_sizes, int n_in,
                              void* d_out, int out_size, void* d_ws, size_t ws_size,
                              hipStream_t stream) {
    const float* m    = (const float*)d_in[0];
    const int*   row  = (const int*)d_in[1];
    const int*   col  = (const int*)d_in[2];
    const float* vals = (const float*)d_in[3];
    float*       out  = (float*)d_out;

    const int nnz = in_sizes[1];
    const int n_rows = in_sizes[0] / D;   // 50000

    NaiveMerge_spmm_kernel<<<n_rows, D, 0, stream>>>(m, row, col, vals, out, nnz);
}

// Round 4
// 124.278 us; speedup vs baseline: 2.1137x; 2.1137x over previous
//
#include <hip/hip_runtime.h>
#include <hip/hip_fp16.h>

// SpMM: out = fp32( segment_sum( fp16(m)[col] * fp16(vals)[:,None], row ) )
// N=50000, NNZ=800000 (row sorted), D=256.
//
// Kernel 1: build row_ptr[N+1] in d_ws via parallel binary search (independent
//           threads — removes the dependent binary-search chain from the SpMM).
// Kernel 2: one 64-lane wave per output row; lane l owns float4 d=[4l,4l+3].
//           Per edge: one global_load_dwordx4 (1 KiB per wave, coalesced).
//           2-deep unroll => 2 gathers in flight per wave; 32 waves/CU hide
//           the col->gather latency chain.

#define D 256
#define D4 64   // D/4

__device__ __forceinline__ int lower_bound_dev(const int* __restrict__ a, int n, int key) {
    int lo = 0, hi = n;
    while (lo < hi) {
        int mid = (lo + hi) >> 1;
        if (a[mid] < key) lo = mid + 1;
        else hi = mid;
    }
    return lo;
}

__global__ __launch_bounds__(256) void build_row_ptr_kernel(
        const int* __restrict__ row, int nnz, int n_rows,
        int* __restrict__ row_ptr) {
    const int r = blockIdx.x * blockDim.x + threadIdx.x;
    if (r > n_rows) return;
    row_ptr[r] = lower_bound_dev(row, nnz, r);
}

__global__ __launch_bounds__(256) void spmm_wave_per_row_kernel(
        const float4* __restrict__ m4,
        const int* __restrict__ row_ptr,      // may be null -> fallback search
        const int* __restrict__ row,
        const int* __restrict__ col,
        const float* __restrict__ vals,
        float4* __restrict__ out4,
        int n_rows, int nnz) {
    const int wid  = threadIdx.x >> 6;     // wave 0..3
    const int lane = threadIdx.x & 63;
    const int r = blockIdx.x * 4 + wid;
    if (r >= n_rows) return;

    int start, end;
    if (row_ptr) {
        start = row_ptr[r];
        end   = row_ptr[r + 1];
    } else {
        start = lower_bound_dev(row, nnz, r);
        end   = lower_bound_dev(row, nnz, r + 1);
    }

    float acc0 = 0.f, acc1 = 0.f, acc2 = 0.f, acc3 = 0.f;

    int e = start;
    // 2-deep unroll: two independent col->gather chains in flight.
    for (; e + 1 < end; e += 2) {
        const int   c0 = col[e],     c1 = col[e + 1];
        const float v0 = vals[e],    v1 = vals[e + 1];
        const float4 a = m4[(size_t)c0 * D4 + lane];
        const float4 b = m4[(size_t)c1 * D4 + lane];
        const __half h0 = __float2half(v0);
        const __half h1 = __float2half(v1);
        acc0 += __half2float(__hmul(__float2half(a.x), h0));
        acc1 += __half2float(__hmul(__float2half(a.y), h0));
        acc2 += __half2float(__hmul(__float2half(a.z), h0));
        acc3 += __half2float(__hmul(__float2half(a.w), h0));
        acc0 += __half2float(__hmul(__float2half(b.x), h1));
        acc1 += __half2float(__hmul(__float2half(b.y), h1));
        acc2 += __half2float(__hmul(__float2half(b.z), h1));
        acc3 += __half2float(__hmul(__float2half(b.w), h1));
    }
    if (e < end) {
        const int   c0 = col[e];
        const float v0 = vals[e];
        const float4 a = m4[(size_t)c0 * D4 + lane];
        const __half h0 = __float2half(v0);
        acc0 += __half2float(__hmul(__float2half(a.x), h0));
        acc1 += __half2float(__hmul(__float2half(a.y), h0));
        acc2 += __half2float(__hmul(__float2half(a.z), h0));
        acc3 += __half2float(__hmul(__float2half(a.w), h0));
    }

    out4[(size_t)r * D4 + lane] = make_float4(acc0, acc1, acc2, acc3);
}

extern "C" void kernel_launch(void* const* d_in, const int* in_sizes, int n_in,
                              void* d_out, int out_size, void* d_ws, size_t ws_size,
                              hipStream_t stream) {
    const float* m    = (const float*)d_in[0];
    const int*   row  = (const int*)d_in[1];
    const int*   col  = (const int*)d_in[2];
    const float* vals = (const float*)d_in[3];
    float*       out  = (float*)d_out;

    const int nnz    = in_sizes[1];
    const int n_rows = in_sizes[0] / D;   // 50000

    int* row_ptr = nullptr;
    if (ws_size >= (size_t)(n_rows + 1) * sizeof(int)) {
        row_ptr = (int*)d_ws;
        const int nthreads = n_rows + 1;
        build_row_ptr_kernel<<<(nthreads + 255) / 256, 256, 0, stream>>>(
            row, nnz, n_rows, row_ptr);
    }

    const int blocks = (n_rows + 3) / 4;   // 4 rows (waves) per block
    spmm_wave_per_row_kernel<<<blocks, 256, 0, stream>>>(
        (const float4*)m, row_ptr, row, col, vals, (float4*)out, n_rows, nnz);
}

// Round 5
// 114.534 us; speedup vs baseline: 2.2936x; 1.0851x over previous
//
#include <hip/hip_runtime.h>
#include <hip/hip_fp16.h>

// SpMM: out = fp32( segment_sum( fp16(m)[col] * fp16(vals)[:,None], row ) )
// N=50000, NNZ=800000 (row sorted), D=256.
//
// Round 5 structure:
//  Kernel P (prep): convert m fp32->fp16 into d_ws (halves gather bytes; the
//    reference computes in fp16 anyway) AND build row_ptr[N+1] via parallel
//    binary search. One fused streaming kernel.
//  Kernel S (spmm): one 64-lane wave per row, lane owns 4 halfs (8 B).
//    Edges processed in batches of 8: hoist 8 col/vals loads (issue
//    together), issue 8 gathers back-to-back (8 concurrent 512 B gathers
//    per wave), then packed __hmul2 + fp32 accumulate.
//  Fallback to fp32 path if ws_size is too small.

#define D   256
#define D4  64   // D/4 floats
#define D8  32   // D/8

__device__ __forceinline__ int lower_bound_dev(const int* __restrict__ a, int n, int key) {
    int lo = 0, hi = n;
    while (lo < hi) {
        int mid = (lo + hi) >> 1;
        if (a[mid] < key) lo = mid + 1;
        else hi = mid;
    }
    return lo;
}

// ---------------- prep: m -> fp16, row -> row_ptr ----------------
__global__ __launch_bounds__(256) void prep_kernel(
        const float4* __restrict__ m4,
        const int* __restrict__ row,
        int nnz, int n_rows,
        uint4* __restrict__ mh_vec,      // fp16 m, 8 halfs per uint4
        int* __restrict__ row_ptr) {
    const int tid = blockIdx.x * blockDim.x + threadIdx.x;
    const int nth = gridDim.x * blockDim.x;

    const int n_items = n_rows * D8;     // groups of 8 floats
    for (int i = tid; i < n_items; i += nth) {
        const float4 a = m4[2 * i];
        const float4 b = m4[2 * i + 1];
        union { __half h[8]; uint4 u; } pk;
        pk.h[0] = __float2half(a.x); pk.h[1] = __float2half(a.y);
        pk.h[2] = __float2half(a.z); pk.h[3] = __float2half(a.w);
        pk.h[4] = __float2half(b.x); pk.h[5] = __float2half(b.y);
        pk.h[6] = __float2half(b.z); pk.h[7] = __float2half(b.w);
        mh_vec[i] = pk.u;
    }

    for (int r = tid; r <= n_rows; r += nth) {
        row_ptr[r] = lower_bound_dev(row, nnz, r);
    }
}

// ---------------- main: fp16 gather SpMM ----------------
__global__ __launch_bounds__(256) void spmm_fp16_kernel(
        const __half* __restrict__ mh,
        const int* __restrict__ row_ptr,
        const int* __restrict__ col,
        const float* __restrict__ vals,
        float4* __restrict__ out4,
        int n_rows) {
    const int wid  = threadIdx.x >> 6;
    const int lane = threadIdx.x & 63;
    const int r = blockIdx.x * 4 + wid;
    if (r >= n_rows) return;

    const int start = row_ptr[r];
    const int end   = row_ptr[r + 1];

    float a0 = 0.f, a1 = 0.f, a2 = 0.f, a3 = 0.f;

    for (int e0 = start; e0 < end; e0 += 8) {
        const int n = end - e0;          // wave-uniform

        int   c[8];
        float v[8];
        #pragma unroll
        for (int j = 0; j < 8; ++j) {
            if (j < n) { c[j] = col[e0 + j]; v[j] = vals[e0 + j]; }
            else       { c[j] = 0;           v[j] = 0.f; }
        }

        uint2 g[8];
        #pragma unroll
        for (int j = 0; j < 8; ++j) {
            if (j < n) {
                g[j] = ((const uint2*)(mh + (size_t)c[j] * D))[lane];
            }
        }

        #pragma unroll
        for (int j = 0; j < 8; ++j) {
            if (j < n) {
                const __half2 hv = __float2half2_rn(v[j]);
                const __half2 h01 = __builtin_bit_cast(__half2, g[j].x);
                const __half2 h23 = __builtin_bit_cast(__half2, g[j].y);
                const __half2 p01 = __hmul2(h01, hv);
                const __half2 p23 = __hmul2(h23, hv);
                const float2 f0 = __half22float2(p01);
                const float2 f1 = __half22float2(p23);
                a0 += f0.x; a1 += f0.y; a2 += f1.x; a3 += f1.y;
            }
        }
    }

    out4[(size_t)r * D4 + lane] = make_float4(a0, a1, a2, a3);
}

// ---------------- fallback (round-4 fp32 path) ----------------
__global__ __launch_bounds__(256) void spmm_fp32_kernel(
        const float4* __restrict__ m4,
        const int* __restrict__ row,
        const int* __restrict__ col,
        const float* __restrict__ vals,
        float4* __restrict__ out4,
        int n_rows, int nnz) {
    const int wid  = threadIdx.x >> 6;
    const int lane = threadIdx.x & 63;
    const int r = blockIdx.x * 4 + wid;
    if (r >= n_rows) return;

    const int start = lower_bound_dev(row, nnz, r);
    const int end   = lower_bound_dev(row, nnz, r + 1);

    float a0 = 0.f, a1 = 0.f, a2 = 0.f, a3 = 0.f;
    for (int e = start; e < end; ++e) {
        const int   c = col[e];
        const float v = vals[e];
        const float4 a = m4[(size_t)c * D4 + lane];
        const __half hv = __float2half(v);
        a0 += __half2float(__hmul(__float2half(a.x), hv));
        a1 += __half2float(__hmul(__float2half(a.y), hv));
        a2 += __half2float(__hmul(__float2half(a.z), hv));
        a3 += __half2float(__hmul(__float2half(a.w), hv));
    }
    out4[(size_t)r * D4 + lane] = make_float4(a0, a1, a2, a3);
}

extern "C" void kernel_launch(void* const* d_in, const int* in_sizes, int n_in,
                              void* d_out, int out_size, void* d_ws, size_t ws_size,
                              hipStream_t stream) {
    const float* m    = (const float*)d_in[0];
    const int*   row  = (const int*)d_in[1];
    const int*   col  = (const int*)d_in[2];
    const float* vals = (const float*)d_in[3];
    float*       out  = (float*)d_out;

    const int nnz    = in_sizes[1];
    const int n_rows = in_sizes[0] / D;   // 50000

    const size_t mh_bytes = (size_t)n_rows * D * sizeof(__half);      // 25.6 MB
    const size_t rp_bytes = (size_t)(n_rows + 1) * sizeof(int);       // 200 KB
    const int blocks = (n_rows + 3) / 4;  // 4 rows (waves) per block

    if (ws_size >= mh_bytes + rp_bytes) {
        __half* mh      = (__half*)d_ws;
        int*    row_ptr = (int*)((char*)d_ws + mh_bytes);

        const int n_items = n_rows * D8;              // 1.6M convert items
        const int pblocks = (n_items + 255) / 256;    // 6250 blocks
        prep_kernel<<<pblocks, 256, 0, stream>>>(
            (const float4*)m, row, nnz, n_rows, (uint4*)mh, row_ptr);

        spmm_fp16_kernel<<<blocks, 256, 0, stream>>>(
            mh, row_ptr, col, vals, (float4*)out, n_rows);
    } else {
        spmm_fp32_kernel<<<blocks, 256, 0, stream>>>(
            (const float4*)m, row, col, vals, (float4*)out, n_rows, nnz);
    }
}

// Round 6
// 81.968 us; speedup vs baseline: 3.2048x; 1.3973x over previous
//
#include <hip/hip_runtime.h>
#include <hip/hip_fp16.h>

// SpMM: out = fp32( segment_sum( fp16(m)[col] * fp16(vals)[:,None], row ) )
// N=50000, NNZ=800000 (row sorted), D=256.
//
// Round 6: restore memory-level parallelism in the gather loop.
//  - Round-5 post-mortem: VGPR_Count=28 proved the compiler fused the
//    predicated issue/consume loops -> 1 gather in flight. Fix:
//    * branch-free staging (clamped index + value zeroing, no exec-mask ops)
//    * 8 unconditional gathers per chunk (pads gather col[end-1], v=0)
//    * sched_barrier(0) between gather-issue and consume
//    * software-pipelined col/vals staging for the next chunk.
//  Kernel P (prep): m fp32->fp16 in d_ws + row_ptr via parallel binary search.
//  Kernel S (spmm): one 64-lane wave per row; lane owns 4 halfs (8 B).

#define D   256
#define D4  64   // D/4 floats
#define D8  32   // D/8

__device__ __forceinline__ int lower_bound_dev(const int* __restrict__ a, int n, int key) {
    int lo = 0, hi = n;
    while (lo < hi) {
        int mid = (lo + hi) >> 1;
        if (a[mid] < key) lo = mid + 1;
        else hi = mid;
    }
    return lo;
}

// ---------------- prep: m -> fp16, row -> row_ptr ----------------
__global__ __launch_bounds__(256) void prep_kernel(
        const float4* __restrict__ m4,
        const int* __restrict__ row,
        int nnz, int n_rows,
        uint4* __restrict__ mh_vec,      // fp16 m, 8 halfs per uint4
        int* __restrict__ row_ptr) {
    const int tid = blockIdx.x * blockDim.x + threadIdx.x;
    const int nth = gridDim.x * blockDim.x;

    const int n_items = n_rows * D8;     // groups of 8 floats
    for (int i = tid; i < n_items; i += nth) {
        const float4 a = m4[2 * i];
        const float4 b = m4[2 * i + 1];
        union { __half h[8]; uint4 u; } pk;
        pk.h[0] = __float2half(a.x); pk.h[1] = __float2half(a.y);
        pk.h[2] = __float2half(a.z); pk.h[3] = __float2half(a.w);
        pk.h[4] = __float2half(b.x); pk.h[5] = __float2half(b.y);
        pk.h[6] = __float2half(b.z); pk.h[7] = __float2half(b.w);
        mh_vec[i] = pk.u;
    }

    for (int r = tid; r <= n_rows; r += nth) {
        row_ptr[r] = lower_bound_dev(row, nnz, r);
    }
}

// ---------------- main: fp16 gather SpMM, pipelined 8-wide MLP ----------------
__global__ __launch_bounds__(256) void spmm_fp16_kernel(
        const __half* __restrict__ mh,
        const int* __restrict__ row_ptr,
        const int* __restrict__ col,
        const float* __restrict__ vals,
        float4* __restrict__ out4,
        int n_rows) {
    const int wid  = threadIdx.x >> 6;
    const int lane = threadIdx.x & 63;
    const int r = blockIdx.x * 4 + wid;
    if (r >= n_rows) return;

    const int start = row_ptr[r];
    const int end   = row_ptr[r + 1];

    float a0 = 0.f, a1 = 0.f, a2 = 0.f, a3 = 0.f;

    if (start < end) {
        const int last = end - 1;
        int   c[8];
        float v[8];
        // stage chunk 0 — branch-free: clamped index, zeroed value for pads
        #pragma unroll
        for (int j = 0; j < 8; ++j) {
            const int e  = start + j;
            const int ec = e < end ? e : last;
            c[j] = col[ec];
            const float vv = vals[ec];
            v[j] = e < end ? vv : 0.f;
        }

        int base = start;
        while (true) {
            // issue 8 independent gathers (unconditional — pads are v=0)
            uint2 g[8];
            #pragma unroll
            for (int j = 0; j < 8; ++j) {
                g[j] = ((const uint2*)(mh + ((size_t)c[j] << 8)))[lane];
            }

            // stage next chunk's col/vals while gathers are in flight
            const int nbase = base + 8;
            const bool more = nbase < end;   // wave-uniform
            int   cn[8];
            float vn[8];
            if (more) {
                #pragma unroll
                for (int j = 0; j < 8; ++j) {
                    const int e  = nbase + j;
                    const int ec = e < end ? e : last;
                    cn[j] = col[ec];
                    const float vv = vals[ec];
                    vn[j] = e < end ? vv : 0.f;
                }
            }

            // keep all loads above the consume phase
            __builtin_amdgcn_sched_barrier(0);

            #pragma unroll
            for (int j = 0; j < 8; ++j) {
                const __half2 hv  = __float2half2_rn(v[j]);
                const __half2 h01 = __builtin_bit_cast(__half2, g[j].x);
                const __half2 h23 = __builtin_bit_cast(__half2, g[j].y);
                const float2 f0 = __half22float2(__hmul2(h01, hv));
                const float2 f1 = __half22float2(__hmul2(h23, hv));
                a0 += f0.x; a1 += f0.y; a2 += f1.x; a3 += f1.y;
            }

            if (!more) break;
            base = nbase;
            #pragma unroll
            for (int j = 0; j < 8; ++j) { c[j] = cn[j]; v[j] = vn[j]; }
        }
    }

    out4[(size_t)r * D4 + lane] = make_float4(a0, a1, a2, a3);
}

// ---------------- fallback (round-4 fp32 path) ----------------
__global__ __launch_bounds__(256) void spmm_fp32_kernel(
        const float4* __restrict__ m4,
        const int* __restrict__ row,
        const int* __restrict__ col,
        const float* __restrict__ vals,
        float4* __restrict__ out4,
        int n_rows, int nnz) {
    const int wid  = threadIdx.x >> 6;
    const int lane = threadIdx.x & 63;
    const int r = blockIdx.x * 4 + wid;
    if (r >= n_rows) return;

    const int start = lower_bound_dev(row, nnz, r);
    const int end   = lower_bound_dev(row, nnz, r + 1);

    float a0 = 0.f, a1 = 0.f, a2 = 0.f, a3 = 0.f;
    for (int e = start; e < end; ++e) {
        const int   c = col[e];
        const float v = vals[e];
        const float4 a = m4[(size_t)c * D4 + lane];
        const __half hv = __float2half(v);
        a0 += __half2float(__hmul(__float2half(a.x), hv));
        a1 += __half2float(__hmul(__float2half(a.y), hv));
        a2 += __half2float(__hmul(__float2half(a.z), hv));
        a3 += __half2float(__hmul(__float2half(a.w), hv));
    }
    out4[(size_t)r * D4 + lane] = make_float4(a0, a1, a2, a3);
}

extern "C" void kernel_launch(void* const* d_in, const int* in_sizes, int n_in,
                              void* d_out, int out_size, void* d_ws, size_t ws_size,
                              hipStream_t stream) {
    const float* m    = (const float*)d_in[0];
    const int*   row  = (const int*)d_in[1];
    const int*   col  = (const int*)d_in[2];
    const float* vals = (const float*)d_in[3];
    float*       out  = (float*)d_out;

    const int nnz    = in_sizes[1];
    const int n_rows = in_sizes[0] / D;   // 50000

    const size_t mh_bytes = (size_t)n_rows * D * sizeof(__half);      // 25.6 MB
    const size_t rp_bytes = (size_t)(n_rows + 1) * sizeof(int);       // 200 KB
    const int blocks = (n_rows + 3) / 4;  // 4 rows (waves) per block

    if (ws_size >= mh_bytes + rp_bytes) {
        __half* mh      = (__half*)d_ws;
        int*    row_ptr = (int*)((char*)d_ws + mh_bytes);

        const int n_items = n_rows * D8;              // 1.6M convert items
        const int pblocks = (n_items + 255) / 256;    // 6250 blocks
        prep_kernel<<<pblocks, 256, 0, stream>>>(
            (const float4*)m, row, nnz, n_rows, (uint4*)mh, row_ptr);

        spmm_fp16_kernel<<<blocks, 256, 0, stream>>>(
            mh, row_ptr, col, vals, (float4*)out, n_rows);
    } else {
        spmm_fp32_kernel<<<blocks, 256, 0, stream>>>(
            (const float4*)m, row, col, vals, (float4*)out, n_rows, nnz);
    }
}

// Round 7
// 77.602 us; speedup vs baseline: 3.3851x; 1.0563x over previous
//
#include <hip/hip_runtime.h>
#include <hip/hip_fp16.h>

// SpMM: out = fp32( segment_sum( fp16(m)[col] * fp16(vals)[:,None], row ) )
// N=50000, NNZ=800000 (row sorted), D=256.
//
// Round 7: cut serial latency windows + consume VALU.
//  - 16-deep gather batches (whole row in one window for deg<=16 rows).
//  - fp16 pk_fma accumulation (2 chains), fp32 flush once per chunk:
//    ~4 VALU/edge vs ~11.
//  - full chunks: unclamped contiguous col/vals loads (merge to dwordx4);
//    clamped branch only for the final partial chunk (stays in [start,end),
//    never OOB).
//  - readfirstlane(start/end): staging control flow + addresses to SALU.

#define D   256
#define D4  64   // D/4 floats
#define D8  32   // D/8

__device__ __forceinline__ int lower_bound_dev(const int* __restrict__ a, int n, int key) {
    int lo = 0, hi = n;
    while (lo < hi) {
        int mid = (lo + hi) >> 1;
        if (a[mid] < key) lo = mid + 1;
        else hi = mid;
    }
    return lo;
}

// ---------------- prep: m -> fp16, row -> row_ptr ----------------
__global__ __launch_bounds__(256) void prep_kernel(
        const float4* __restrict__ m4,
        const int* __restrict__ row,
        int nnz, int n_rows,
        uint4* __restrict__ mh_vec,      // fp16 m, 8 halfs per uint4
        int* __restrict__ row_ptr) {
    const int tid = blockIdx.x * blockDim.x + threadIdx.x;
    const int nth = gridDim.x * blockDim.x;

    const int n_items = n_rows * D8;     // groups of 8 floats
    for (int i = tid; i < n_items; i += nth) {
        const float4 a = m4[2 * i];
        const float4 b = m4[2 * i + 1];
        union { __half h[8]; uint4 u; } pk;
        pk.h[0] = __float2half(a.x); pk.h[1] = __float2half(a.y);
        pk.h[2] = __float2half(a.z); pk.h[3] = __float2half(a.w);
        pk.h[4] = __float2half(b.x); pk.h[5] = __float2half(b.y);
        pk.h[6] = __float2half(b.z); pk.h[7] = __float2half(b.w);
        mh_vec[i] = pk.u;
    }

    for (int r = tid; r <= n_rows; r += nth) {
        row_ptr[r] = lower_bound_dev(row, nnz, r);
    }
}

// ---------------- main: fp16 gather SpMM, 16-wide MLP ----------------
__global__ __launch_bounds__(256) void spmm_fp16_kernel(
        const __half* __restrict__ mh,
        const int* __restrict__ row_ptr,
        const int* __restrict__ col,
        const float* __restrict__ vals,
        float4* __restrict__ out4,
        int n_rows) {
    const int wid  = threadIdx.x >> 6;
    const int lane = threadIdx.x & 63;
    const int r = blockIdx.x * 4 + wid;
    if (r >= n_rows) return;

    const int start = __builtin_amdgcn_readfirstlane(row_ptr[r]);
    const int end   = __builtin_amdgcn_readfirstlane(row_ptr[r + 1]);

    const uint2* __restrict__ mh2 = (const uint2*)mh;

    float a0 = 0.f, a1 = 0.f, a2 = 0.f, a3 = 0.f;

    for (int e0 = start; e0 < end; e0 += 16) {
        int   c[16];
        float v[16];
        if (e0 + 16 <= end) {
            // full chunk: contiguous unclamped loads (merge to dwordx4)
            #pragma unroll
            for (int j = 0; j < 16; ++j) {
                c[j] = col[e0 + j];
                v[j] = vals[e0 + j];
            }
        } else {
            // final partial chunk: clamp into [start,end), zero pad values
            const int last = end - 1;
            #pragma unroll
            for (int j = 0; j < 16; ++j) {
                const int e  = e0 + j;
                const int ec = e < end ? e : last;
                c[j] = col[ec];
                const float vv = vals[ec];
                v[j] = e < end ? vv : 0.f;
            }
        }

        // 16 independent gathers in flight (512 B per wave each)
        uint2 g[16];
        #pragma unroll
        for (int j = 0; j < 16; ++j) {
            g[j] = mh2[((size_t)c[j] << 6) + lane];
        }

        __builtin_amdgcn_sched_barrier(0);

        // fp16 packed-fma accumulation, two chains, fp32 flush per chunk
        __half2 s01a = __float2half2_rn(0.f);
        __half2 s23a = __float2half2_rn(0.f);
        __half2 s01b = __float2half2_rn(0.f);
        __half2 s23b = __float2half2_rn(0.f);
        #pragma unroll
        for (int j = 0; j < 16; j += 2) {
            const __half2 hva = __float2half2_rn(v[j]);
            s01a = __hfma2(__builtin_bit_cast(__half2, g[j].x), hva, s01a);
            s23a = __hfma2(__builtin_bit_cast(__half2, g[j].y), hva, s23a);
            const __half2 hvb = __float2half2_rn(v[j + 1]);
            s01b = __hfma2(__builtin_bit_cast(__half2, g[j + 1].x), hvb, s01b);
            s23b = __hfma2(__builtin_bit_cast(__half2, g[j + 1].y), hvb, s23b);
        }
        float2 f;
        f = __half22float2(s01a); a0 += f.x; a1 += f.y;
        f = __half22float2(s01b); a0 += f.x; a1 += f.y;
        f = __half22float2(s23a); a2 += f.x; a3 += f.y;
        f = __half22float2(s23b); a2 += f.x; a3 += f.y;
    }

    out4[(size_t)r * D4 + lane] = make_float4(a0, a1, a2, a3);
}

// ---------------- fallback (fp32 path, no workspace) ----------------
__global__ __launch_bounds__(256) void spmm_fp32_kernel(
        const float4* __restrict__ m4,
        const int* __restrict__ row,
        const int* __restrict__ col,
        const float* __restrict__ vals,
        float4* __restrict__ out4,
        int n_rows, int nnz) {
    const int wid  = threadIdx.x >> 6;
    const int lane = threadIdx.x & 63;
    const int r = blockIdx.x * 4 + wid;
    if (r >= n_rows) return;

    const int start = lower_bound_dev(row, nnz, r);
    const int end   = lower_bound_dev(row, nnz, r + 1);

    float a0 = 0.f, a1 = 0.f, a2 = 0.f, a3 = 0.f;
    for (int e = start; e < end; ++e) {
        const int   c = col[e];
        const float v = vals[e];
        const float4 a = m4[(size_t)c * D4 + lane];
        const __half hv = __float2half(v);
        a0 += __half2float(__hmul(__float2half(a.x), hv));
        a1 += __half2float(__hmul(__float2half(a.y), hv));
        a2 += __half2float(__hmul(__float2half(a.z), hv));
        a3 += __half2float(__hmul(__float2half(a.w), hv));
    }
    out4[(size_t)r * D4 + lane] = make_float4(a0, a1, a2, a3);
}

extern "C" void kernel_launch(void* const* d_in, const int* in_sizes, int n_in,
                              void* d_out, int out_size, void* d_ws, size_t ws_size,
                              hipStream_t stream) {
    const float* m    = (const float*)d_in[0];
    const int*   row  = (const int*)d_in[1];
    const int*   col  = (const int*)d_in[2];
    const float* vals = (const float*)d_in[3];
    float*       out  = (float*)d_out;

    const int nnz    = in_sizes[1];
    const int n_rows = in_sizes[0] / D;   // 50000

    const size_t mh_bytes = (size_t)n_rows * D * sizeof(__half);      // 25.6 MB
    const size_t rp_bytes = (size_t)(n_rows + 1) * sizeof(int);       // 200 KB
    const int blocks = (n_rows + 3) / 4;  // 4 rows (waves) per block

    if (ws_size >= mh_bytes + rp_bytes) {
        __half* mh      = (__half*)d_ws;
        int*    row_ptr = (int*)((char*)d_ws + mh_bytes);

        const int n_items = n_rows * D8;              // 1.6M convert items
        const int pblocks = (n_items + 255) / 256;    // 6250 blocks
        prep_kernel<<<pblocks, 256, 0, stream>>>(
            (const float4*)m, row, nnz, n_rows, (uint4*)mh, row_ptr);

        spmm_fp16_kernel<<<blocks, 256, 0, stream>>>(
            mh, row_ptr, col, vals, (float4*)out, n_rows);
    } else {
        spmm_fp32_kernel<<<blocks, 256, 0, stream>>>(
            (const float4*)m, row, col, vals, (float4*)out, n_rows, nnz);
    }
}